// Round 13
// baseline (897.876 us; speedup 1.0000x reference)
//
#include <hip/hip_runtime.h>

#define RNN_B 64
#define RNN_T 1024
#define RNN_D 256
#define RNN_H 256
#define NB 16          // batches per scan workgroup (4 WGs)
#define GEMM_ROWS 64   // (b,t) rows per gemm block

typedef __attribute__((ext_vector_type(8))) short bf16x8;
typedef __attribute__((ext_vector_type(4))) float f32x4;

__device__ __forceinline__ unsigned short f32_to_bf16_rne(float f) {
  unsigned u = __builtin_bit_cast(unsigned, f);
  u += 0x7fffu + ((u >> 16) & 1u);
  return (unsigned short)(u >> 16);
}

// branch-free tanh: 1 - 2/(exp2(2*log2e*x)+1); exact at +/-inf, ~1e-6 abs err
__device__ __forceinline__ float tanh_fast(float x) {
  const float e = x * 2.8853900817779268f;  // 2*log2(e)
  float t;
  asm("v_exp_f32 %0, %1" : "=v"(t) : "v"(e));
  const float r = __builtin_amdgcn_rcpf(t + 1.0f);
  return fmaf(-2.0f, r, 1.0f);
}

// swizzled u16 index of h[batch][col]; row stride 512B, XOR spreads rows
// across 16B bank-slots (rows r and r+8 alias -> 2-way per phase = free).
__device__ __forceinline__ int hidx(int batch, int col) {
  return (batch * 512 + ((col * 2) ^ ((batch & 7) << 4))) >> 1;
}

__device__ __forceinline__ void wg_barrier_lds_only() {
  // drain LDS ops only; deliberately NOT vmcnt -> global xp prefetch and h
  // stores stay in flight across steps (avoids __syncthreads' vmcnt(0) drain)
  asm volatile("s_waitcnt lgkmcnt(0)" ::: "memory");
  __builtin_amdgcn_sched_barrier(0);
  __builtin_amdgcn_s_barrier();
  __builtin_amdgcn_sched_barrier(0);
}

// ---------------------------------------------------------------------------
// Kernel 0: Wx (f32 [k][col]) -> Wxb (bf16, fragment order [col][kc][lq][j])
// so gemm waves load A'-frags as coalesced 16B chunks.
// ---------------------------------------------------------------------------
__global__ __launch_bounds__(1024) void wx_prep_kernel(
    const float* __restrict__ Wx, unsigned short* __restrict__ Wxb) {
  const int g = blockIdx.x * 1024 + threadIdx.x;  // 8192 frags
  const int lq = g & 3;
  const int kc = (g >> 2) & 7;
  const int col = g >> 5;
  unsigned short v[8];
#pragma unroll
  for (int j = 0; j < 8; ++j) {
    const int k = kc * 32 + lq * 8 + j;
    v[j] = f32_to_bf16_rne(Wx[(size_t)k * RNN_H + col]);
  }
  *reinterpret_cast<uint4*>(&Wxb[(size_t)g * 8]) =
      *reinterpret_cast<const uint4*>(v);
}

// ---------------------------------------------------------------------------
// Kernel 1 (MFMA): xp^T = Wx^T (A', VGPRs from Wxb) x x^T (B', LDS bf16).
// 1024 blocks x 1024 thr (16 waves); block handles 64 (b,t) rows.
// At its memory roofline (~36 us incl. prep) — unchanged from R10.
// ---------------------------------------------------------------------------
__global__ __launch_bounds__(1024) void xp_gemm_mfma(
    const float* __restrict__ x, const unsigned short* __restrict__ Wxb,
    const float* __restrict__ bias, float* __restrict__ xp) {
  __shared__ unsigned short xs[GEMM_ROWS * 256];  // 32 KB

  const int tid = threadIdx.x;
  const int wid = tid >> 6;      // 0..15 = outcol tile
  const int lane = tid & 63;
  const int lrow = lane & 15;    // n-index: t-row within group
  const int lq = lane >> 4;      // k-quad / D row-quad
  const size_t row0 = (size_t)blockIdx.x * GEMM_ROWS;

  // A'-frags from Wxb: coalesced 16B loads (issue first, latency overlaps
  // with the staging below)
  bf16x8 wfrag[8];
  {
    const int col = wid * 16 + lrow;
#pragma unroll
    for (int kc = 0; kc < 8; ++kc)
      wfrag[kc] = *reinterpret_cast<const bf16x8*>(
          &Wxb[(size_t)((col * 8 + kc) * 4 + lq) * 8]);
  }
  const f32x4 bseed = *reinterpret_cast<const f32x4*>(&bias[wid * 16 + lq * 4]);

  // stage 64 x-rows as bf16 (each thread: 16 cols of one row)
  {
    const int row = tid >> 4;            // 0..63
    const int c16 = (tid & 15) * 16;     // col base
    const float* src = x + (row0 + row) * RNN_D + c16;
    unsigned p[8];
#pragma unroll
    for (int q = 0; q < 4; ++q) {
      const f32x4 v = *reinterpret_cast<const f32x4*>(src + 4 * q);
      asm("v_cvt_pk_bf16_f32 %0, %1, %2" : "=v"(p[2 * q]) : "v"(v[0]), "v"(v[1]));
      asm("v_cvt_pk_bf16_f32 %0, %1, %2" : "=v"(p[2 * q + 1]) : "v"(v[2]), "v"(v[3]));
    }
    const int swz = (row & 7) << 4;
    const int b0 = row * 512 + ((c16 * 2) ^ swz);
    const int b1 = row * 512 + ((c16 * 2 + 16) ^ swz);
    *reinterpret_cast<uint4*>(&xs[b0 >> 1]) = *reinterpret_cast<uint4*>(&p[0]);
    *reinterpret_cast<uint4*>(&xs[b1 >> 1]) = *reinterpret_cast<uint4*>(&p[4]);
  }
  __syncthreads();

#pragma unroll
  for (int rg = 0; rg < GEMM_ROWS / 16; ++rg) {
    // B'-frags: row = rg*16 + lrow, k-slice = kc*32 + lq*8 (+8)
    bf16x8 hf[8];
#pragma unroll
    for (int kc = 0; kc < 8; ++kc) {
      const int off =
          ((rg * 16 + lrow) * 512 + ((kc * 64 + lq * 16) ^ ((lrow & 7) << 4))) >> 1;
      hf[kc] = *reinterpret_cast<const bf16x8*>(&xs[off]);
    }
    f32x4 accE = bseed;
    f32x4 accO = {0.f, 0.f, 0.f, 0.f};
#pragma unroll
    for (int kc = 0; kc < 8; kc += 2) {
      accE = __builtin_amdgcn_mfma_f32_16x16x32_bf16(wfrag[kc], hf[kc], accE,
                                                     0, 0, 0);
      accO = __builtin_amdgcn_mfma_f32_16x16x32_bf16(wfrag[kc + 1], hf[kc + 1],
                                                     accO, 0, 0, 0);
    }
    const f32x4 r = accE + accO;
    float* dst = xp + (row0 + rg * 16 + lrow) * RNN_H + wid * 16 + lq * 4;
    *reinterpret_cast<f32x4*>(dst) = r;
  }
}

// ---------------------------------------------------------------------------
// One recurrence step. Swapped-operand MFMA: S^T = Wh^T (A') x h^T (B').
// 8 waves x 2 tiles: wave wid owns outcol tiles {2*wid, 2*wid+1}; ONE set of
// B'-frag reads (8 x ds_read_b128) feeds BOTH tiles' MFMA chains -> LDS
// instructions per WG-step: 64 reads + 16 writes (vs 144 at 1 tile/wave).
// Full n: all 16 lanes = real batches (no masking). Two independent 8-deep
// MFMA chains seeded with xp (C-in). SLOT = step index in 4-step unroll;
// RD = SLOT&1 is the LDS h buffer.
// ---------------------------------------------------------------------------
template <int SLOT>
__device__ __forceinline__ void rnn_step(
    unsigned short (&hb)[2][NB * 256], const bf16x8 (&wfrag)[2][8],
    f32x4 (&xq)[4][2], const float* xp_base, float* h_base, float* hl_st,
    bool last, int lrow, int lq, int wid) {
  constexpr int RD = SLOT & 1;
  const f32x4 xc0 = xq[SLOT][0];  // consume (loaded 4 steps ago)
  const f32x4 xc1 = xq[SLOT][1];

  // 1) B'-fragments of h from LDS first (critical path, shared by tiles)
  bf16x8 hf[8];
#pragma unroll
  for (int kc = 0; kc < 8; ++kc) {
    const int off =
        (lrow * 512 + ((kc * 64 + lq * 16) ^ ((lrow & 7) << 4))) >> 1;
    hf[kc] = *reinterpret_cast<const bf16x8*>(&hb[RD][off]);
  }
  // 2) refill slot: prefetch xp for step t+SLOT+4 (both tiles)
  xq[SLOT][0] = *reinterpret_cast<const f32x4*>(&xp_base[SLOT * RNN_H]);
  xq[SLOT][1] = *reinterpret_cast<const f32x4*>(&xp_base[SLOT * RNN_H + 16]);

  // 3) MFMA: two independent 8-deep chains (one per tile), seeded with xp
  f32x4 a0 = xc0, a1 = xc1;
  __builtin_amdgcn_s_setprio(1);
#pragma unroll
  for (int kc = 0; kc < 8; ++kc) {
    a0 = __builtin_amdgcn_mfma_f32_16x16x32_bf16(wfrag[0][kc], hf[kc], a0, 0,
                                                 0, 0);
    a1 = __builtin_amdgcn_mfma_f32_16x16x32_bf16(wfrag[1][kc], hf[kc], a1, 0,
                                                 0, 0);
  }
  __builtin_amdgcn_s_setprio(0);

  // 4) tanh; float4 global stores; packed bf16 b64 -> other LDS buffer
  f32x4 h0v, h1v;
#pragma unroll
  for (int r = 0; r < 4; ++r) {
    h0v[r] = tanh_fast(a0[r]);
    h1v[r] = tanh_fast(a1[r]);
  }
  *reinterpret_cast<f32x4*>(&h_base[SLOT * RNN_H]) = h0v;
  *reinterpret_cast<f32x4*>(&h_base[SLOT * RNN_H + 16]) = h1v;
  if (last) {
    *reinterpret_cast<f32x4*>(hl_st) = h0v;
    *reinterpret_cast<f32x4*>(hl_st + 16) = h1v;
  }
  {
    unsigned p0, p1, p2, p3;
    asm("v_cvt_pk_bf16_f32 %0, %1, %2" : "=v"(p0) : "v"(h0v[0]), "v"(h0v[1]));
    asm("v_cvt_pk_bf16_f32 %0, %1, %2" : "=v"(p1) : "v"(h0v[2]), "v"(h0v[3]));
    asm("v_cvt_pk_bf16_f32 %0, %1, %2" : "=v"(p2) : "v"(h1v[0]), "v"(h1v[1]));
    asm("v_cvt_pk_bf16_f32 %0, %1, %2" : "=v"(p3) : "v"(h1v[2]), "v"(h1v[3]));
    const int swz = (lrow & 7) << 4;
    uint2 pk0; pk0.x = p0; pk0.y = p1;
    uint2 pk1; pk1.x = p2; pk1.y = p3;
    const int b0 = lrow * 512 + (((2 * wid) * 32 + lq * 8) ^ swz);
    const int b1 = lrow * 512 + (((2 * wid + 1) * 32 + lq * 8) ^ swz);
    *reinterpret_cast<uint2*>(&hb[RD ^ 1][b0 >> 1]) = pk0;
    *reinterpret_cast<uint2*>(&hb[RD ^ 1][b1 >> 1]) = pk1;
  }

  // 5) LDS-only barrier (global ops remain in flight)
  wg_barrier_lds_only();
}

// ---------------------------------------------------------------------------
// Kernel 2: MFMA recurrence. 4 WGs x 16 batches, 8 waves (512 thr) each;
// 2 outcol tiles per wave; xp prefetched 4 steps deep.
// ---------------------------------------------------------------------------
__global__ __launch_bounds__(512, 2) void rnn_rec_mfma(
    const float* __restrict__ Wh, const float* __restrict__ h0, float* out,
    float* h_last) {
  __shared__ unsigned short hb[2][NB * 256];  // 16 KB

  const int bg = blockIdx.x;     // batch group 0..3
  const int tid = threadIdx.x;
  const int wid = tid >> 6;      // 0..7 -> tiles {2*wid, 2*wid+1}
  const int lane = tid & 63;
  const int lrow = lane & 15;    // batch / A' m-index (all real)
  const int lq = lane >> 4;      // k-quad / C row-quad

  // ---- one-time: Wh^T A'-fragments (f32 -> bf16, RNE) into VGPRs -------
  bf16x8 wfrag[2][8];
#pragma unroll
  for (int i = 0; i < 2; ++i) {
    const int col = (2 * wid + i) * 16 + lrow;
#pragma unroll
    for (int kc = 0; kc < 8; ++kc) {
      bf16x8 v;
#pragma unroll
      for (int j = 0; j < 8; ++j) {
        const int k = kc * 32 + lq * 8 + j;
        v[j] = (short)f32_to_bf16_rne(Wh[(size_t)k * RNN_H + col]);
      }
      wfrag[i][kc] = v;
    }
  }

  // ---- one-time: h0 -> hb[0] (bf16, swizzled); 16 rows x 256 cols ------
  {
    const int b = tid >> 5;            // 0..15
    const int c0 = (tid & 31) * 8;     // 8 cols per thread
#pragma unroll
    for (int c = 0; c < 8; ++c) {
      hb[0][hidx(b, c0 + c)] =
          f32_to_bf16_rne(h0[(size_t)(bg * NB + b) * RNN_H + c0 + c]);
    }
  }

  // per-lane global pointers: batch = lrow, tile0 cols + tile1 = +16
  float* outb = out + (size_t)bg * NB * RNN_T * RNN_H;
  const int col0 = (2 * wid) * 16 + lq * 4;
  float* hbase = outb + (size_t)lrow * RNN_T * RNN_H + col0;
  float* hl_st = h_last + (size_t)(bg * NB + lrow) * RNN_H + col0;

  // prologue: xp rows 0..3 (both tiles) into the 4-slot register pipeline
  f32x4 xq[4][2];
#pragma unroll
  for (int s = 0; s < 4; ++s) {
    xq[s][0] = *reinterpret_cast<const f32x4*>(&hbase[s * RNN_H]);
    xq[s][1] = *reinterpret_cast<const f32x4*>(&hbase[s * RNN_H + 16]);
  }
  const float* xp_base = hbase + 4 * RNN_H;  // -> xp row t+4
  float* h_base = hbase;                     // -> h row t

  wg_barrier_lds_only();  // h0 staging visible

#pragma unroll 1
  for (int t = 0; t < RNN_T; t += 4) {
    const bool lastp = (t == RNN_T - 4);
    rnn_step<0>(hb, wfrag, xq, xp_base, h_base, hl_st, false, lrow, lq, wid);
    rnn_step<1>(hb, wfrag, xq, xp_base, h_base, hl_st, false, lrow, lq, wid);
    rnn_step<2>(hb, wfrag, xq, xp_base, h_base, hl_st, false, lrow, lq, wid);
    rnn_step<3>(hb, wfrag, xq, xp_base, h_base, hl_st, lastp, lrow, lq, wid);
    xp_base += 4 * RNN_H;
    h_base += 4 * RNN_H;
  }
}

extern "C" void kernel_launch(void* const* d_in, const int* in_sizes, int n_in,
                              void* d_out, int out_size, void* d_ws, size_t ws_size,
                              hipStream_t stream) {
  const float* x = (const float*)d_in[0];
  const float* h0 = (const float*)d_in[1];
  const float* Wx = (const float*)d_in[2];
  const float* Wh = (const float*)d_in[3];
  const float* bias = (const float*)d_in[4];
  float* out = (float*)d_out;
  float* h_last = out + (size_t)RNN_B * RNN_T * RNN_H;
  unsigned short* Wxb = (unsigned short*)d_ws;  // 128 KB

  wx_prep_kernel<<<8, 1024, 0, stream>>>(Wx, Wxb);
  xp_gemm_mfma<<<RNN_B * RNN_T / GEMM_ROWS, 1024, 0, stream>>>(x, Wxb, bias,
                                                               out);
  rnn_rec_mfma<<<RNN_B / NB, 512, 0, stream>>>(Wh, h0, out, h_last);
}

// Round 14
// 649.059 us; speedup vs baseline: 1.3833x; 1.3833x over previous
//
#include <hip/hip_runtime.h>

#define RNN_B 64
#define RNN_T 1024
#define RNN_D 256
#define RNN_H 256
#define NB 4           // batches per scan workgroup (16 WGs)
#define GEMM_ROWS 64   // (b,t) rows per gemm block

typedef __attribute__((ext_vector_type(8))) short bf16x8;
typedef __attribute__((ext_vector_type(4))) float f32x4;

__device__ __forceinline__ unsigned short f32_to_bf16_rne(float f) {
  unsigned u = __builtin_bit_cast(unsigned, f);
  u += 0x7fffu + ((u >> 16) & 1u);
  return (unsigned short)(u >> 16);
}

// branch-free tanh: 1 - 2/(exp2(2*log2e*x)+1); exact at +/-inf, ~1e-6 abs err
__device__ __forceinline__ float tanh_fast(float x) {
  const float e = x * 2.8853900817779268f;  // 2*log2(e)
  float t;
  asm("v_exp_f32 %0, %1" : "=v"(t) : "v"(e));
  const float r = __builtin_amdgcn_rcpf(t + 1.0f);
  return fmaf(-2.0f, r, 1.0f);
}

// swizzled u16 index of h[batch][col]; row stride 512B, XOR spreads rows
// across 16B bank-slots.
__device__ __forceinline__ int hidx(int batch, int col) {
  return ((batch & 7) * 512 + ((col * 2) ^ ((batch & 7) << 4))) >> 1;
}

__device__ __forceinline__ void wg_barrier_lds_only() {
  // drain LDS ops only; deliberately NOT vmcnt -> global xp prefetch and h
  // stores stay in flight across steps (avoids __syncthreads' vmcnt(0) drain)
  asm volatile("s_waitcnt lgkmcnt(0)" ::: "memory");
  __builtin_amdgcn_sched_barrier(0);
  __builtin_amdgcn_s_barrier();
  __builtin_amdgcn_sched_barrier(0);
}

// ---------------------------------------------------------------------------
// Kernel 0: Wx (f32 [k][col]) -> Wxb (bf16, fragment order [col][kc][lq][j])
// so gemm waves load A'-frags as coalesced 16B chunks.
// ---------------------------------------------------------------------------
__global__ __launch_bounds__(1024) void wx_prep_kernel(
    const float* __restrict__ Wx, unsigned short* __restrict__ Wxb) {
  const int g = blockIdx.x * 1024 + threadIdx.x;  // 8192 frags
  const int lq = g & 3;
  const int kc = (g >> 2) & 7;
  const int col = g >> 5;
  unsigned short v[8];
#pragma unroll
  for (int j = 0; j < 8; ++j) {
    const int k = kc * 32 + lq * 8 + j;
    v[j] = f32_to_bf16_rne(Wx[(size_t)k * RNN_H + col]);
  }
  *reinterpret_cast<uint4*>(&Wxb[(size_t)g * 8]) =
      *reinterpret_cast<const uint4*>(v);
}

// ---------------------------------------------------------------------------
// Kernel 1 (MFMA): xp^T = Wx^T (A', VGPRs from Wxb) x x^T (B', LDS bf16).
// 1024 blocks x 1024 thr (16 waves); block handles 64 (b,t) rows.
// At its memory roofline (~36 us incl. prep).
// ---------------------------------------------------------------------------
__global__ __launch_bounds__(1024) void xp_gemm_mfma(
    const float* __restrict__ x, const unsigned short* __restrict__ Wxb,
    const float* __restrict__ bias, float* __restrict__ xp) {
  __shared__ unsigned short xs[GEMM_ROWS * 256];  // 32 KB

  const int tid = threadIdx.x;
  const int wid = tid >> 6;      // 0..15 = outcol tile
  const int lane = tid & 63;
  const int lrow = lane & 15;    // n-index: t-row within group
  const int lq = lane >> 4;      // k-quad / D row-quad
  const size_t row0 = (size_t)blockIdx.x * GEMM_ROWS;

  // A'-frags from Wxb: coalesced 16B loads (issue first, latency overlaps
  // with the staging below)
  bf16x8 wfrag[8];
  {
    const int col = wid * 16 + lrow;
#pragma unroll
    for (int kc = 0; kc < 8; ++kc)
      wfrag[kc] = *reinterpret_cast<const bf16x8*>(
          &Wxb[(size_t)((col * 8 + kc) * 4 + lq) * 8]);
  }
  const f32x4 bseed = *reinterpret_cast<const f32x4*>(&bias[wid * 16 + lq * 4]);

  // stage 64 x-rows as bf16 (each thread: 16 cols of one row)
  {
    const int row = tid >> 4;            // 0..63
    const int c16 = (tid & 15) * 16;     // col base
    const float* src = x + (row0 + row) * RNN_D + c16;
    unsigned p[8];
#pragma unroll
    for (int q = 0; q < 4; ++q) {
      const f32x4 v = *reinterpret_cast<const f32x4*>(src + 4 * q);
      asm("v_cvt_pk_bf16_f32 %0, %1, %2" : "=v"(p[2 * q]) : "v"(v[0]), "v"(v[1]));
      asm("v_cvt_pk_bf16_f32 %0, %1, %2" : "=v"(p[2 * q + 1]) : "v"(v[2]), "v"(v[3]));
    }
    const int swz = (row & 7) << 4;
    const int b0 = row * 512 + ((c16 * 2) ^ swz);
    const int b1 = row * 512 + ((c16 * 2 + 16) ^ swz);
    *reinterpret_cast<uint4*>(&xs[b0 >> 1]) = *reinterpret_cast<uint4*>(&p[0]);
    *reinterpret_cast<uint4*>(&xs[b1 >> 1]) = *reinterpret_cast<uint4*>(&p[4]);
  }
  __syncthreads();

#pragma unroll
  for (int rg = 0; rg < GEMM_ROWS / 16; ++rg) {
    // B'-frags: row = rg*16 + lrow, k-slice = kc*32 + lq*8 (+8)
    bf16x8 hf[8];
#pragma unroll
    for (int kc = 0; kc < 8; ++kc) {
      const int off =
          ((rg * 16 + lrow) * 512 + ((kc * 64 + lq * 16) ^ ((lrow & 7) << 4))) >> 1;
      hf[kc] = *reinterpret_cast<const bf16x8*>(&xs[off]);
    }
    f32x4 accE = bseed;
    f32x4 accO = {0.f, 0.f, 0.f, 0.f};
#pragma unroll
    for (int kc = 0; kc < 8; kc += 2) {
      accE = __builtin_amdgcn_mfma_f32_16x16x32_bf16(wfrag[kc], hf[kc], accE,
                                                     0, 0, 0);
      accO = __builtin_amdgcn_mfma_f32_16x16x32_bf16(wfrag[kc + 1], hf[kc + 1],
                                                     accO, 0, 0, 0);
    }
    const f32x4 r = accE + accO;
    float* dst = xp + (row0 + rg * 16 + lrow) * RNN_H + wid * 16 + lq * 4;
    *reinterpret_cast<f32x4*>(dst) = r;
  }
}

// ---------------------------------------------------------------------------
// One recurrence step. Swapped-operand MFMA: S^T = Wh^T (A') x h^T (B').
// 16 waves; wave wid owns ONE outcol tile. Lanes with lrow >= NB are
// exec-masked off LDS/global (their MFMA output is garbage, never stored).
// acc = single 8-deep MFMA chain seeded with xp (C-in). SLOT = step index
// in 4-step unroll; RD = SLOT&1 is the LDS h buffer.
// ---------------------------------------------------------------------------
template <int SLOT>
__device__ __forceinline__ void rnn_step(
    unsigned short (&hb)[2][NB * 256], const bf16x8 (&wfrag)[8],
    f32x4 (&xq)[4], const float* xp_base, float* h_base, float* hl_st,
    bool last, bool act, int lrow, int lq, int wid) {
  constexpr int RD = SLOT & 1;
  const f32x4 xc = xq[SLOT];  // consume (loaded 4 steps ago)

  // 1) B'-fragments of h from LDS first (critical path), masked to NB rows
  bf16x8 hf[8];
  if (act) {
#pragma unroll
    for (int kc = 0; kc < 8; ++kc) {
      const int off = (lrow * 512 + ((kc * 64 + lq * 16) ^ (lrow << 4))) >> 1;
      hf[kc] = *reinterpret_cast<const bf16x8*>(&hb[RD][off]);
    }
    // 2) refill slot: prefetch xp for step t+SLOT+4 (consumed 4 steps later)
    xq[SLOT] = *reinterpret_cast<const f32x4*>(&xp_base[SLOT * RNN_H]);
  }

  // 3) MFMA: single chain of 8, seeded with xp
  f32x4 acc = xc;
  __builtin_amdgcn_s_setprio(1);
#pragma unroll
  for (int kc = 0; kc < 8; ++kc)
    acc = __builtin_amdgcn_mfma_f32_16x16x32_bf16(wfrag[kc], hf[kc], acc, 0, 0,
                                                  0);
  __builtin_amdgcn_s_setprio(0);

  // 4) tanh; float4 global store; packed bf16 b64 -> other LDS buffer
  f32x4 h;
#pragma unroll
  for (int r = 0; r < 4; ++r) h[r] = tanh_fast(acc[r]);
  if (act) {
    *reinterpret_cast<f32x4*>(&h_base[SLOT * RNN_H]) = h;
    if (last) *reinterpret_cast<f32x4*>(hl_st) = h;

    unsigned p0, p1;
    asm("v_cvt_pk_bf16_f32 %0, %1, %2" : "=v"(p0) : "v"(h[0]), "v"(h[1]));
    asm("v_cvt_pk_bf16_f32 %0, %1, %2" : "=v"(p1) : "v"(h[2]), "v"(h[3]));
    uint2 pk; pk.x = p0; pk.y = p1;
    const int byte = lrow * 512 + ((wid * 32 + lq * 8) ^ (lrow << 4));
    *reinterpret_cast<uint2*>(&hb[RD ^ 1][byte >> 1]) = pk;
  }

  // 5) LDS-only barrier (global ops remain in flight)
  wg_barrier_lds_only();
}

// ---------------------------------------------------------------------------
// Kernel 2: MFMA recurrence. 16 WGs x 4 batches, 16 waves (1024 thr) each;
// xp prefetched 4 steps deep.
// ---------------------------------------------------------------------------
__global__ __launch_bounds__(1024, 4) void rnn_rec_mfma(
    const float* __restrict__ Wh, const float* __restrict__ h0, float* out,
    float* h_last) {
  __shared__ unsigned short hb[2][NB * 256];

  const int bg = blockIdx.x;     // batch group 0..15
  const int tid = threadIdx.x;
  const int wid = tid >> 6;      // 0..15 = outcol tile
  const int lane = tid & 63;
  const int lrow = lane & 15;    // batch (if < NB) / A' m-index
  const int lq = lane >> 4;      // k-quad / C row-quad
  const bool act = lrow < NB;

  // ---- one-time: Wh^T A'-fragments (f32 -> bf16, RNE) into VGPRs -------
  bf16x8 wfrag[8];
  {
    const int col = wid * 16 + lrow;
#pragma unroll
    for (int kc = 0; kc < 8; ++kc) {
      bf16x8 v;
#pragma unroll
      for (int j = 0; j < 8; ++j) {
        const int k = kc * 32 + lq * 8 + j;
        v[j] = (short)f32_to_bf16_rne(Wh[(size_t)k * RNN_H + col]);
      }
      wfrag[kc] = v;
    }
  }

  // ---- one-time: h0 -> hb[0] (bf16, swizzled); NB rows x 256 cols ------
  {
    const int b = tid >> 8;            // 0..3
    const int c = tid & 255;           // col
    hb[0][hidx(b, c)] =
        f32_to_bf16_rne(h0[(size_t)(bg * NB + b) * RNN_H + c]);
  }

  // per-lane global pointers: batch = lrow (if act), 4 consecutive cols
  float* outb = out + (size_t)bg * NB * RNN_T * RNN_H;
  const int col0 = wid * 16 + lq * 4;
  float* hbase = outb + (size_t)(lrow & (NB - 1)) * RNN_T * RNN_H + col0;
  float* hl_st = h_last + (size_t)(bg * NB + (lrow & (NB - 1))) * RNN_H + col0;

  // prologue: xp rows 0..3 into the 4-slot register pipeline
  f32x4 xq[4];
  if (act) {
#pragma unroll
    for (int s = 0; s < 4; ++s)
      xq[s] = *reinterpret_cast<const f32x4*>(&hbase[s * RNN_H]);
  }
  const float* xp_base = hbase + 4 * RNN_H;  // -> xp row t+4
  float* h_base = hbase;                     // -> h row t

  wg_barrier_lds_only();  // h0 staging visible

#pragma unroll 1
  for (int t = 0; t < RNN_T; t += 4) {
    const bool lastp = (t == RNN_T - 4);
    rnn_step<0>(hb, wfrag, xq, xp_base, h_base, hl_st, false, act, lrow, lq, wid);
    rnn_step<1>(hb, wfrag, xq, xp_base, h_base, hl_st, false, act, lrow, lq, wid);
    rnn_step<2>(hb, wfrag, xq, xp_base, h_base, hl_st, false, act, lrow, lq, wid);
    rnn_step<3>(hb, wfrag, xq, xp_base, h_base, hl_st, lastp, act, lrow, lq, wid);
    xp_base += 4 * RNN_H;
    h_base += 4 * RNN_H;
  }
}

extern "C" void kernel_launch(void* const* d_in, const int* in_sizes, int n_in,
                              void* d_out, int out_size, void* d_ws, size_t ws_size,
                              hipStream_t stream) {
  const float* x = (const float*)d_in[0];
  const float* h0 = (const float*)d_in[1];
  const float* Wx = (const float*)d_in[2];
  const float* Wh = (const float*)d_in[3];
  const float* bias = (const float*)d_in[4];
  float* out = (float*)d_out;
  float* h_last = out + (size_t)RNN_B * RNN_T * RNN_H;
  unsigned short* Wxb = (unsigned short*)d_ws;  // 128 KB

  wx_prep_kernel<<<8, 1024, 0, stream>>>(Wx, Wxb);
  xp_gemm_mfma<<<RNN_B * RNN_T / GEMM_ROWS, 1024, 0, stream>>>(x, Wxb, bias,
                                                               out);
  rnn_rec_mfma<<<RNN_B / NB, 1024, 0, stream>>>(Wh, h0, out, h_last);
}